// Round 14
// baseline (54.653 us; speedup 1.0000x reference)
//
#include <hip/hip_runtime.h>
#include <hip/hip_bf16.h>

#define NQ     8
#define SEQL   128
#define BATCHN 256
#define EMBED  512
#define DIN    520          // EMBED + NQ
#define GSTR   32           // 4 gates * 8 qubits
#define INV2PI 0.15915494309189535f
#define WROW   524          // Wlds padded row (shorts) -> conflict-free b128

typedef __attribute__((ext_vector_type(8))) short  bf16x8;
typedef __attribute__((ext_vector_type(4))) float  f32x4;
typedef unsigned int uint2v __attribute__((ext_vector_type(2)));

__device__ __forceinline__ short f2bf(float f) {
    union { __hip_bfloat16 h; short s; } u;
    u.h = __float2bfloat16(f);          // RNE convert
    return u.s;
}

// ---------------------------------------------------------------------------
// DPP helpers: row_shr:N -> lane i gets i-N ; row_shl:N -> i+N ;
//              row_ror:8 -> lane i gets i^8 within its 16-lane row
// ---------------------------------------------------------------------------
#define DPP_QP(a,b,c,d) ((a)|((b)<<2)|((c)<<4)|((d)<<6))
#define DPP_SHL(n) (0x100+(n))
#define DPP_SHR(n) (0x110+(n))
#define DPP_ROR(n) (0x120+(n))

template<int CTRL>
__device__ __forceinline__ float updpf(float old_, float src) {
    return __int_as_float(__builtin_amdgcn_update_dpp(
        __float_as_int(old_), __float_as_int(src), CTRL, 0xF, 0xF, false));
}

// value at lane^16 (XOR-extract, semantics-proof)
__device__ __forceinline__ float xor16f(float x) {
    unsigned xu = (unsigned)__float_as_int(x);
    uint2v r = __builtin_amdgcn_permlane16_swap(xu, xu, false, false);
    return __int_as_float((int)(r.x ^ r.y ^ xu));
}

__device__ __forceinline__ float frcp(float x) { return __builtin_amdgcn_rcpf(x); }
__device__ __forceinline__ float fexp2(float x) { return __builtin_amdgcn_exp2f(x); }

#define LOG2E  1.4426950408889634f
#define LOG2E2 2.8853900817779268f

// one LSTM step (r8-proven math)
#define QSTEP(GV) do {                                                        \
    float sA = fmaf(H[0],Whp[0],fmaf(H[1],Whp[1],fmaf(H[2],Whp[2],H[3]*Whp[3]))); \
    float sB = fmaf(H[4],Whp[4],fmaf(H[5],Whp[5],fmaf(H[6],Whp[6],H[7]*Whp[7]))); \
    float cs = __builtin_amdgcn_cosf((GV) + sA + sB);                         \
    float p = cs, s;                                                          \
    s = updpf<DPP_SHR(1)>(1.0f, p); p *= (m1 ? s : 1.0f);                     \
    s = updpf<DPP_SHR(2)>(1.0f, p); p *= (m2 ? s : 1.0f);                     \
    s = updpf<DPP_SHR(4)>(1.0f, p); p *= (m4 ? s : 1.0f);                     \
    float v = jz ? 1.0f : cs;                                                 \
    v *= updpf<DPP_QP(1,0,3,2)>(v, v);                                        \
    v *= updpf<DPP_QP(2,3,0,1)>(v, v);                                        \
    float xl = updpf<DPP_SHL(4)>(v, v);                                       \
    float xr = updpf<DPP_SHR(4)>(v, v);                                       \
    v *= (m4 ? xr : xl);                                                      \
    float qv = jz ? v : p;                                                    \
    float act = fmaf(sk, frcp(1.0f + fexp2(ek * qv)), ok);                    \
    float A_  = act;                                                          \
    float B8  = updpf<DPP_ROR(8)>(A_, A_);                                    \
    float C16 = xor16f(A_);                                                   \
    float D24 = updpf<DPP_ROR(8)>(C16, C16);                                  \
    float fv = (g==0) ? A_ : (g==1) ? B8 : (g==2) ? C16 : D24;                \
    float iv = (g==1) ? A_ : (g==0) ? B8 : (g==3) ? C16 : D24;                \
    float uv = (g==2) ? A_ : (g==3) ? B8 : (g==0) ? C16 : D24;                \
    float ov = (g==3) ? A_ : (g==2) ? B8 : (g==1) ? C16 : D24;                \
    c_own = fmaf(fv, c_own, iv * uv);                                         \
    float tc = fmaf(-2.0f, frcp(1.0f + fexp2(LOG2E2 * c_own)), 1.0f);         \
    h_own = ov * tc;                                                          \
    H[0] = h_own;                                                             \
    H[1] = updpf<DPP_QP(1,0,3,2)>(H[0], H[0]);                                \
    H[2] = updpf<DPP_QP(2,3,0,1)>(H[0], H[0]);                                \
    H[3] = updpf<DPP_QP(2,3,0,1)>(H[1], H[1]);                                \
    _Pragma("unroll")                                                         \
    for (int rr = 0; rr < 4; ++rr) {                                          \
        float yl = updpf<DPP_SHL(4)>(H[rr], H[rr]);                           \
        float yr = updpf<DPP_SHR(4)>(H[rr], H[rr]);                           \
        H[4 + rr] = m4 ? yr : yl;                                             \
    }                                                                         \
} while (0)

// MFMA one 8-step chunk from prefetched ua/va regs -> gbuf -> gv[8]
// A rows: m = t_off (rows 8-15 duplicate 0-7, outputs unused).
// C layout (proven r7/r8): col = lane&15, row = 4*(lane>>4)+reg.
#define MFMA_PHASE() do {                                                     \
    f32x4 acc0 = {0.f,0.f,0.f,0.f};                                           \
    f32x4 acc1 = {0.f,0.f,0.f,0.f};                                           \
    _Pragma("unroll")                                                         \
    for (int kc = 0; kc < 16; ++kc) {                                         \
        bf16x8 a;                                                             \
        a[0]=f2bf(ua[kc].x); a[1]=f2bf(ua[kc].y);                             \
        a[2]=f2bf(ua[kc].z); a[3]=f2bf(ua[kc].w);                             \
        a[4]=f2bf(va[kc].x); a[5]=f2bf(va[kc].y);                             \
        a[6]=f2bf(va[kc].z); a[7]=f2bf(va[kc].w);                             \
        const int kl_ = kc * 32 + q * 8;                                      \
        bf16x8 b0 = *reinterpret_cast<const bf16x8*>(&Wlds[lm][kl_]);         \
        bf16x8 b1 = *reinterpret_cast<const bf16x8*>(&Wlds[16 + lm][kl_]);    \
        acc0 = __builtin_amdgcn_mfma_f32_16x16x32_bf16(a, b0, acc0, 0, 0, 0); \
        acc1 = __builtin_amdgcn_mfma_f32_16x16x32_bf16(a, b1, acc1, 0, 0, 0); \
    }                                                                         \
    __syncthreads();                                                          \
    if (q < 2) {                                                              \
        _Pragma("unroll")                                                     \
        for (int r_ = 0; r_ < 4; ++r_) {                                      \
            gbuf[(4*q + r_) * GSTR + lm]      = fmaf(acc0[r_], INV2PI, bc0);  \
            gbuf[(4*q + r_) * GSTR + 16 + lm] = fmaf(acc1[r_], INV2PI, bc1);  \
        }                                                                     \
    }                                                                         \
    __syncthreads();                                                          \
    _Pragma("unroll")                                                         \
    for (int s_ = 0; s_ < 8; ++s_) gv[s_] = gbuf[s_ * GSTR + l32];            \
} while (0)

// ---------------------------------------------------------------------------
// Fully fused kernel: 256 blocks x 1 wave; block = one batch row.
//   Per 8-step chunk: [issue tok(c+2)] [issue emb loads(c+1), 128 VGPR]
//   [8 serial QSTEPs] [MFMA(c+1) -> gbuf -> gv]. GEMM + gather hide under
//   the serial chain. No workspace G, no second kernel, no cross-block sync.
// ---------------------------------------------------------------------------
__global__ __launch_bounds__(64, 1)
void k_fused(const int* __restrict__ sent, const float* __restrict__ emb,
             const float* __restrict__ Wf, const float* __restrict__ Wi,
             const float* __restrict__ Wu, const float* __restrict__ Wo,
             const float* __restrict__ bf, const float* __restrict__ bi,
             const float* __restrict__ bu, const float* __restrict__ bo,
             const float* __restrict__ thf, const float* __restrict__ thi,
             const float* __restrict__ thu, const float* __restrict__ tho,
             float* __restrict__ out)
{
    __shared__ short Wlds[32][WROW];     // 33.5 KB bf16, [c][k 0..511]
    __shared__ float gbuf[8 * GSTR];     // 1 KB chunk bounce

    const int tid = threadIdx.x;         // 0..63
    const int b   = blockIdx.x;          // batch row
    const int l32 = tid & 31;
    const int g   = l32 >> 3;            // gate 0..3 (f,i,u,o)
    const int j   = l32 & 7;             // qubit
    const int lm  = tid & 15;            // MFMA A-row / B-col
    const int q   = tid >> 4;            // MFMA k-quarter
    const int trow = lm & 7;             // timestep-in-chunk for A row

    // ---- stage W (EMBED cols) -> bf16 LDS ----
    {
        const int c = tid & 31, seg = tid >> 5;      // seg 0..1 x 256 floats
        const int gg = c >> 3, jj = c & 7;
        const float* W = (gg==0) ? Wf : (gg==1) ? Wi : (gg==2) ? Wu : Wo;
        const float* src = W + (size_t)jj * DIN + seg * 256;
        #pragma unroll
        for (int p = 0; p < 32; ++p) {
            float4 u = *reinterpret_cast<const float4*>(src + p * 8);
            float4 v = *reinterpret_cast<const float4*>(src + p * 8 + 4);
            bf16x8 pk;
            pk[0]=f2bf(u.x); pk[1]=f2bf(u.y); pk[2]=f2bf(u.z); pk[3]=f2bf(u.w);
            pk[4]=f2bf(v.x); pk[5]=f2bf(v.y); pk[6]=f2bf(v.z); pk[7]=f2bf(v.w);
            *reinterpret_cast<bf16x8*>(&Wlds[c][seg * 256 + p * 8]) = pk;
        }
    }

    // epilogue fold constants for this lane's two C columns (lm, 16+lm)
    float bc0, bc1;
    {
        const int g0 = lm >> 3, j0 = lm & 7;         // gate 0/1 (f,i)
        const float* B0 = (g0==0) ? bf  : bi;
        const float* T0 = (g0==0) ? thf : thi;
        bc0 = (B0[j0] + T0[j0]) * INV2PI;
        const int g1 = lm >> 3, j1 = lm & 7;         // gate 2/3 (u,o)
        const float* B1 = (g1==0) ? bu  : bo;
        const float* T1 = (g1==0) ? thu : tho;
        bc1 = (B1[j1] + T1[j1]) * INV2PI;
    }

    // QSTEP weights: permuted, pre-scaled; dot = sum_r H[r]*Whp[r], H[r]=h[j^r]
    const float* Wsel = (g==0) ? Wf : (g==1) ? Wi : (g==2) ? Wu : Wo;
    float Whp[8];
    #pragma unroll
    for (int rr = 0; rr < 8; ++rr)
        Whp[rr] = Wsel[j * DIN + EMBED + (j ^ rr)] * INV2PI;

    __syncthreads();

    // ---- prologue: chunk 0 loads + MFMA ----
    float4 ua[16], va[16];
    float  gv[8];
    int tokC = sent[trow * BATCHN + b];
    {
        const float* ar = emb + (size_t)tokC * EMBED;
        #pragma unroll
        for (int kc = 0; kc < 16; ++kc) {
            ua[kc] = *reinterpret_cast<const float4*>(ar + kc * 32 + q * 8);
            va[kc] = *reinterpret_cast<const float4*>(ar + kc * 32 + q * 8 + 4);
        }
    }
    int tokN = sent[(8 + trow) * BATCHN + b];
    MFMA_PHASE();

    // ---- serial state ----
    float H[8];
    #pragma unroll
    for (int rr = 0; rr < 8; ++rr) H[rr] = 0.f;
    float c_own = 0.f, h_own = 0.f;

    const bool m1 = (j >= 1), m2 = (j >= 2), m4 = (j >= 4), jz = (j == 0);
    const bool isU = (g == 2);
    const float ek = isU ? LOG2E2 : -LOG2E;
    const float sk = isU ? -2.0f  : 1.0f;
    const float ok = isU ? 1.0f   : 0.0f;

    #pragma unroll 1
    for (int c = 0; c < 16; ++c) {
        int tokNN = 0;
        if (c < 14) tokNN = sent[((c + 2) * 8 + trow) * BATCHN + b];
        if (c < 15) {
            const float* an = emb + (size_t)tokN * EMBED;
            #pragma unroll
            for (int kc = 0; kc < 16; ++kc) {
                ua[kc] = *reinterpret_cast<const float4*>(an + kc * 32 + q * 8);
                va[kc] = *reinterpret_cast<const float4*>(an + kc * 32 + q * 8 + 4);
            }
        }
        asm volatile("" ::: "memory");   // pin prefetch issue before QSTEPs

        #pragma unroll
        for (int s = 0; s < 8; ++s) QSTEP(gv[s]);

        if (c < 15) MFMA_PHASE();
        tokN = tokNN;
    }

    if (tid < 8) out[b * NQ + tid] = h_own;   // lanes 0-7: g=0, j=tid
}

// ---------------------------------------------------------------------------
extern "C" void kernel_launch(void* const* d_in, const int* in_sizes, int n_in,
                              void* d_out, int out_size, void* d_ws, size_t ws_size,
                              hipStream_t stream)
{
    const int*   sent = (const int*)  d_in[0];
    // d_in[1] = features : unused by the reference
    const float* emb  = (const float*)d_in[2];
    const float* Wf   = (const float*)d_in[3];
    const float* bf   = (const float*)d_in[4];
    const float* Wi   = (const float*)d_in[5];
    const float* bi   = (const float*)d_in[6];
    const float* Wu   = (const float*)d_in[7];
    const float* bu   = (const float*)d_in[8];
    const float* Wo   = (const float*)d_in[9];
    const float* bo   = (const float*)d_in[10];
    const float* thf  = (const float*)d_in[11];
    const float* thi  = (const float*)d_in[12];
    const float* thu  = (const float*)d_in[13];
    const float* tho  = (const float*)d_in[14];
    float* out = (float*)d_out;

    k_fused<<<BATCHN, 64, 0, stream>>>(sent, emb, Wf, Wi, Wu, Wo,
                                       bf, bi, bu, bo,
                                       thf, thi, thu, tho, out);
}

// Round 15
// 44.214 us; speedup vs baseline: 1.2361x; 1.2361x over previous
//
#include <hip/hip_runtime.h>
#include <hip/hip_bf16.h>

#define NQ     8
#define SEQL   128
#define BATCHN 256
#define EMBED  512
#define DIN    520          // EMBED + NQ
#define GSTR   32           // 4 gates * 8 qubits
#define GBSTR  40           // gbuf row stride: bank=(8r+c)%32 -> <=2-way
#define INV2PI 0.15915494309189535f
#define WROW   524          // Wlds padded row (shorts) -> conflict-free b128

typedef __attribute__((ext_vector_type(8))) short  bf16x8;
typedef __attribute__((ext_vector_type(4))) float  f32x4;
typedef unsigned int uint2v __attribute__((ext_vector_type(2)));

__device__ __forceinline__ short f2bf(float f) {
    union { __hip_bfloat16 h; short s; } u;
    u.h = __float2bfloat16(f);          // RNE convert
    return u.s;
}

// ---------------------------------------------------------------------------
// DPP helpers: row_shr:N -> lane i gets i-N ; row_shl:N -> i+N ;
//              row_ror:8 -> lane i gets i^8 within its 16-lane row
// ---------------------------------------------------------------------------
#define DPP_QP(a,b,c,d) ((a)|((b)<<2)|((c)<<4)|((d)<<6))
#define DPP_SHL(n) (0x100+(n))
#define DPP_SHR(n) (0x110+(n))
#define DPP_ROR(n) (0x120+(n))

template<int CTRL>
__device__ __forceinline__ float updpf(float old_, float src) {
    return __int_as_float(__builtin_amdgcn_update_dpp(
        __float_as_int(old_), __float_as_int(src), CTRL, 0xF, 0xF, false));
}

// value at lane^16 (XOR-extract, semantics-proof)
__device__ __forceinline__ float xor16f(float x) {
    unsigned xu = (unsigned)__float_as_int(x);
    uint2v r = __builtin_amdgcn_permlane16_swap(xu, xu, false, false);
    return __int_as_float((int)(r.x ^ r.y ^ xu));
}

__device__ __forceinline__ float frcp(float x) { return __builtin_amdgcn_rcpf(x); }
__device__ __forceinline__ float fexp2(float x) { return __builtin_amdgcn_exp2f(x); }

#define LOG2E  1.4426950408889634f
#define LOG2E2 2.8853900817779268f

// one LSTM step (r8-proven math)
#define QSTEP(GV) do {                                                        \
    float sA = fmaf(H[0],Whp[0],fmaf(H[1],Whp[1],fmaf(H[2],Whp[2],H[3]*Whp[3]))); \
    float sB = fmaf(H[4],Whp[4],fmaf(H[5],Whp[5],fmaf(H[6],Whp[6],H[7]*Whp[7]))); \
    float cs = __builtin_amdgcn_cosf((GV) + sA + sB);                         \
    float p = cs, s;                                                          \
    s = updpf<DPP_SHR(1)>(1.0f, p); p *= (m1 ? s : 1.0f);                     \
    s = updpf<DPP_SHR(2)>(1.0f, p); p *= (m2 ? s : 1.0f);                     \
    s = updpf<DPP_SHR(4)>(1.0f, p); p *= (m4 ? s : 1.0f);                     \
    float v = jz ? 1.0f : cs;                                                 \
    v *= updpf<DPP_QP(1,0,3,2)>(v, v);                                        \
    v *= updpf<DPP_QP(2,3,0,1)>(v, v);                                        \
    float xl = updpf<DPP_SHL(4)>(v, v);                                       \
    float xr = updpf<DPP_SHR(4)>(v, v);                                       \
    v *= (m4 ? xr : xl);                                                      \
    float qv = jz ? v : p;                                                    \
    float act = fmaf(sk, frcp(1.0f + fexp2(ek * qv)), ok);                    \
    float A_  = act;                                                          \
    float B8  = updpf<DPP_ROR(8)>(A_, A_);                                    \
    float C16 = xor16f(A_);                                                   \
    float D24 = updpf<DPP_ROR(8)>(C16, C16);                                  \
    float fv = (g==0) ? A_ : (g==1) ? B8 : (g==2) ? C16 : D24;                \
    float iv = (g==1) ? A_ : (g==0) ? B8 : (g==3) ? C16 : D24;                \
    float uv = (g==2) ? A_ : (g==3) ? B8 : (g==0) ? C16 : D24;                \
    float ov = (g==3) ? A_ : (g==2) ? B8 : (g==1) ? C16 : D24;                \
    c_own = fmaf(fv, c_own, iv * uv);                                         \
    float tc = fmaf(-2.0f, frcp(1.0f + fexp2(LOG2E2 * c_own)), 1.0f);         \
    h_own = ov * tc;                                                          \
    H[0] = h_own;                                                             \
    H[1] = updpf<DPP_QP(1,0,3,2)>(H[0], H[0]);                                \
    H[2] = updpf<DPP_QP(2,3,0,1)>(H[0], H[0]);                                \
    H[3] = updpf<DPP_QP(2,3,0,1)>(H[1], H[1]);                                \
    _Pragma("unroll")                                                         \
    for (int rr = 0; rr < 4; ++rr) {                                          \
        float yl = updpf<DPP_SHL(4)>(H[rr], H[rr]);                           \
        float yr = updpf<DPP_SHR(4)>(H[rr], H[rr]);                           \
        H[4 + rr] = m4 ? yr : yl;                                             \
    }                                                                         \
} while (0)

// MFMA one 16-step chunk from prefetched ua/va regs -> gbuf -> gv[16]
// A row = lane&15 = timestep-in-chunk (all rows distinct, M=16).
// C layout (proven r7/r8): col = lane&15, row = 4*(lane>>4)+reg.
#define MFMA_PHASE() do {                                                     \
    f32x4 acc0 = {0.f,0.f,0.f,0.f};                                           \
    f32x4 acc1 = {0.f,0.f,0.f,0.f};                                           \
    _Pragma("unroll")                                                         \
    for (int kc = 0; kc < 16; ++kc) {                                         \
        bf16x8 a;                                                             \
        a[0]=f2bf(ua[kc].x); a[1]=f2bf(ua[kc].y);                             \
        a[2]=f2bf(ua[kc].z); a[3]=f2bf(ua[kc].w);                             \
        a[4]=f2bf(va[kc].x); a[5]=f2bf(va[kc].y);                             \
        a[6]=f2bf(va[kc].z); a[7]=f2bf(va[kc].w);                             \
        const int kl_ = kc * 32 + q * 8;                                      \
        bf16x8 b0 = *reinterpret_cast<const bf16x8*>(&Wlds[lm][kl_]);         \
        bf16x8 b1 = *reinterpret_cast<const bf16x8*>(&Wlds[16 + lm][kl_]);    \
        acc0 = __builtin_amdgcn_mfma_f32_16x16x32_bf16(a, b0, acc0, 0, 0, 0); \
        acc1 = __builtin_amdgcn_mfma_f32_16x16x32_bf16(a, b1, acc1, 0, 0, 0); \
    }                                                                         \
    __syncthreads();                                                          \
    _Pragma("unroll")                                                         \
    for (int r_ = 0; r_ < 4; ++r_) {                                          \
        gbuf[(4*q + r_) * GBSTR + lm]      = fmaf(acc0[r_], INV2PI, bc0);     \
        gbuf[(4*q + r_) * GBSTR + 16 + lm] = fmaf(acc1[r_], INV2PI, bc1);     \
    }                                                                         \
    __syncthreads();                                                          \
    _Pragma("unroll")                                                         \
    for (int s_ = 0; s_ < 16; ++s_) gv[s_] = gbuf[s_ * GBSTR + l32];          \
} while (0)

// ---------------------------------------------------------------------------
// Fully fused kernel: 256 blocks x 1 wave; block = one batch row.
//   8 chunks of 16 timesteps. Per chunk: [issue tok(c+2)] [issue emb(c+1),
//   128 VGPR] [16 serial QSTEPs] [MFMA(c+1) -> gbuf -> gv]. The gather+GEMM
//   hide under the ~8.7k-cycle serial chain. One dispatch, no global G.
// ---------------------------------------------------------------------------
__global__ __launch_bounds__(64, 1)
void k_fused(const int* __restrict__ sent, const float* __restrict__ emb,
             const float* __restrict__ Wf, const float* __restrict__ Wi,
             const float* __restrict__ Wu, const float* __restrict__ Wo,
             const float* __restrict__ bf, const float* __restrict__ bi,
             const float* __restrict__ bu, const float* __restrict__ bo,
             const float* __restrict__ thf, const float* __restrict__ thi,
             const float* __restrict__ thu, const float* __restrict__ tho,
             float* __restrict__ out)
{
    __shared__ short Wlds[32][WROW];     // 33.5 KB bf16, [c][k 0..511]
    __shared__ float gbuf[16 * GBSTR];   // 2.56 KB chunk bounce

    const int tid = threadIdx.x;         // 0..63
    const int b   = blockIdx.x;          // batch row
    const int l32 = tid & 31;
    const int g   = l32 >> 3;            // gate 0..3 (f,i,u,o)
    const int j   = l32 & 7;             // qubit
    const int lm  = tid & 15;            // A-row (timestep-in-chunk) / B-col
    const int q   = tid >> 4;            // MFMA k-quarter

    // ---- stage W (EMBED cols) -> bf16 LDS ----
    {
        const int c = tid & 31, seg = tid >> 5;      // seg 0..1 x 256 floats
        const int gg = c >> 3, jj = c & 7;
        const float* W = (gg==0) ? Wf : (gg==1) ? Wi : (gg==2) ? Wu : Wo;
        const float* src = W + (size_t)jj * DIN + seg * 256;
        #pragma unroll
        for (int p = 0; p < 32; ++p) {
            float4 u = *reinterpret_cast<const float4*>(src + p * 8);
            float4 v = *reinterpret_cast<const float4*>(src + p * 8 + 4);
            bf16x8 pk;
            pk[0]=f2bf(u.x); pk[1]=f2bf(u.y); pk[2]=f2bf(u.z); pk[3]=f2bf(u.w);
            pk[4]=f2bf(v.x); pk[5]=f2bf(v.y); pk[6]=f2bf(v.z); pk[7]=f2bf(v.w);
            *reinterpret_cast<bf16x8*>(&Wlds[c][seg * 256 + p * 8]) = pk;
        }
    }

    // epilogue fold constants for this lane's two C columns (lm, 16+lm)
    float bc0, bc1;
    {
        const int g0 = lm >> 3, j0 = lm & 7;         // col lm   -> gate 0/1
        const float* B0 = (g0==0) ? bf  : bi;
        const float* T0 = (g0==0) ? thf : thi;
        bc0 = (B0[j0] + T0[j0]) * INV2PI;
        const float* B1 = (g0==0) ? bu  : bo;        // col 16+lm -> gate 2/3
        const float* T1 = (g0==0) ? thu : tho;
        bc1 = (B1[j0] + T1[j0]) * INV2PI;
    }

    // QSTEP weights: permuted, pre-scaled; dot = sum_r H[r]*Whp[r], H[r]=h[j^r]
    const float* Wsel = (g==0) ? Wf : (g==1) ? Wi : (g==2) ? Wu : Wo;
    float Whp[8];
    #pragma unroll
    for (int rr = 0; rr < 8; ++rr)
        Whp[rr] = Wsel[j * DIN + EMBED + (j ^ rr)] * INV2PI;

    __syncthreads();

    // ---- prologue: chunk 0 loads + MFMA ----
    float4 ua[16], va[16];
    float  gv[16];
    {
        int tok0 = sent[lm * BATCHN + b];
        const float* ar = emb + (size_t)tok0 * EMBED;
        #pragma unroll
        for (int kc = 0; kc < 16; ++kc) {
            ua[kc] = *reinterpret_cast<const float4*>(ar + kc * 32 + q * 8);
            va[kc] = *reinterpret_cast<const float4*>(ar + kc * 32 + q * 8 + 4);
        }
    }
    int tokN = sent[(16 + lm) * BATCHN + b];
    MFMA_PHASE();

    // ---- serial state ----
    float H[8];
    #pragma unroll
    for (int rr = 0; rr < 8; ++rr) H[rr] = 0.f;
    float c_own = 0.f, h_own = 0.f;

    const bool m1 = (j >= 1), m2 = (j >= 2), m4 = (j >= 4), jz = (j == 0);
    const bool isU = (g == 2);
    const float ek = isU ? LOG2E2 : -LOG2E;
    const float sk = isU ? -2.0f  : 1.0f;
    const float ok = isU ? 1.0f   : 0.0f;

    #pragma unroll 1
    for (int c = 0; c < 8; ++c) {
        int tokNN = 0;
        if (c < 6) tokNN = sent[((c + 2) * 16 + lm) * BATCHN + b];
        if (c < 7) {
            const float* an = emb + (size_t)tokN * EMBED;
            #pragma unroll
            for (int kc = 0; kc < 16; ++kc) {
                ua[kc] = *reinterpret_cast<const float4*>(an + kc * 32 + q * 8);
                va[kc] = *reinterpret_cast<const float4*>(an + kc * 32 + q * 8 + 4);
            }
        }
        asm volatile("" ::: "memory");   // pin prefetch issue before QSTEPs

        #pragma unroll
        for (int s = 0; s < 16; ++s) QSTEP(gv[s]);

        if (c < 7) MFMA_PHASE();
        tokN = tokNN;
    }

    if (tid < 8) out[b * NQ + tid] = h_own;   // lanes 0-7: g=0, j=tid
}

// ---------------------------------------------------------------------------
extern "C" void kernel_launch(void* const* d_in, const int* in_sizes, int n_in,
                              void* d_out, int out_size, void* d_ws, size_t ws_size,
                              hipStream_t stream)
{
    const int*   sent = (const int*)  d_in[0];
    // d_in[1] = features : unused by the reference
    const float* emb  = (const float*)d_in[2];
    const float* Wf   = (const float*)d_in[3];
    const float* bf   = (const float*)d_in[4];
    const float* Wi   = (const float*)d_in[5];
    const float* bi   = (const float*)d_in[6];
    const float* Wu   = (const float*)d_in[7];
    const float* bu   = (const float*)d_in[8];
    const float* Wo   = (const float*)d_in[9];
    const float* bo   = (const float*)d_in[10];
    const float* thf  = (const float*)d_in[11];
    const float* thi  = (const float*)d_in[12];
    const float* thu  = (const float*)d_in[13];
    const float* tho  = (const float*)d_in[14];
    float* out = (float*)d_out;

    k_fused<<<BATCHN, 64, 0, stream>>>(sent, emb, Wf, Wi, Wu, Wo,
                                       bf, bi, bu, bo,
                                       thf, thi, thu, tho, out);
}

// Round 16
// 43.966 us; speedup vs baseline: 1.2431x; 1.0057x over previous
//
#include <hip/hip_runtime.h>
#include <hip/hip_bf16.h>

#define NQ     8
#define SEQL   128
#define BATCHN 256
#define EMBED  512
#define DIN    520          // EMBED + NQ
#define GSTR   32           // 4 gates * 8 qubits
#define GBSTR  40           // gbuf row stride: bank=(8r+c)%32 -> <=2-way
#define INV2PI 0.15915494309189535f
#define WROW   524          // Wlds padded row (shorts) -> conflict-free b128

typedef __attribute__((ext_vector_type(8))) short  bf16x8;
typedef __attribute__((ext_vector_type(4))) float  f32x4;
typedef unsigned int uint2v __attribute__((ext_vector_type(2)));

// 8 f32 -> bf16x8 via hardware v_cvt_pk_bf16_f32 (RNE, 4 instr vs ~40 sw-RNE)
__device__ __forceinline__ bf16x8 cvt8(float4 u, float4 v) {
    union { unsigned w[4]; bf16x8 v8; } r;
    asm("v_cvt_pk_bf16_f32 %0, %1, %2" : "=v"(r.w[0]) : "v"(u.x), "v"(u.y));
    asm("v_cvt_pk_bf16_f32 %0, %1, %2" : "=v"(r.w[1]) : "v"(u.z), "v"(u.w));
    asm("v_cvt_pk_bf16_f32 %0, %1, %2" : "=v"(r.w[2]) : "v"(v.x), "v"(v.y));
    asm("v_cvt_pk_bf16_f32 %0, %1, %2" : "=v"(r.w[3]) : "v"(v.z), "v"(v.w));
    return r.v8;
}

// ---------------------------------------------------------------------------
// DPP helpers: row_shr:N -> lane i gets i-N ; row_shl:N -> i+N ;
//              row_ror:8 -> lane i gets i^8 within its 16-lane row
// ---------------------------------------------------------------------------
#define DPP_QP(a,b,c,d) ((a)|((b)<<2)|((c)<<4)|((d)<<6))
#define DPP_SHL(n) (0x100+(n))
#define DPP_SHR(n) (0x110+(n))
#define DPP_ROR(n) (0x120+(n))

template<int CTRL>
__device__ __forceinline__ float updpf(float old_, float src) {
    return __int_as_float(__builtin_amdgcn_update_dpp(
        __float_as_int(old_), __float_as_int(src), CTRL, 0xF, 0xF, false));
}

// value at lane^16 (XOR-extract, semantics-proof)
__device__ __forceinline__ float xor16f(float x) {
    unsigned xu = (unsigned)__float_as_int(x);
    uint2v r = __builtin_amdgcn_permlane16_swap(xu, xu, false, false);
    return __int_as_float((int)(r.x ^ r.y ^ xu));
}

__device__ __forceinline__ float frcp(float x) { return __builtin_amdgcn_rcpf(x); }
__device__ __forceinline__ float fexp2(float x) { return __builtin_amdgcn_exp2f(x); }

#define LOG2E  1.4426950408889634f
#define LOG2E2 2.8853900817779268f

// one LSTM step (r8-proven math)
#define QSTEP(GV) do {                                                        \
    float sA = fmaf(H[0],Whp[0],fmaf(H[1],Whp[1],fmaf(H[2],Whp[2],H[3]*Whp[3]))); \
    float sB = fmaf(H[4],Whp[4],fmaf(H[5],Whp[5],fmaf(H[6],Whp[6],H[7]*Whp[7]))); \
    float cs = __builtin_amdgcn_cosf((GV) + sA + sB);                         \
    float p = cs, s;                                                          \
    s = updpf<DPP_SHR(1)>(1.0f, p); p *= (m1 ? s : 1.0f);                     \
    s = updpf<DPP_SHR(2)>(1.0f, p); p *= (m2 ? s : 1.0f);                     \
    s = updpf<DPP_SHR(4)>(1.0f, p); p *= (m4 ? s : 1.0f);                     \
    float v = jz ? 1.0f : cs;                                                 \
    v *= updpf<DPP_QP(1,0,3,2)>(v, v);                                        \
    v *= updpf<DPP_QP(2,3,0,1)>(v, v);                                        \
    float xl = updpf<DPP_SHL(4)>(v, v);                                       \
    float xr = updpf<DPP_SHR(4)>(v, v);                                       \
    v *= (m4 ? xr : xl);                                                      \
    float qv = jz ? v : p;                                                    \
    float act = fmaf(sk, frcp(1.0f + fexp2(ek * qv)), ok);                    \
    float A_  = act;                                                          \
    float B8  = updpf<DPP_ROR(8)>(A_, A_);                                    \
    float C16 = xor16f(A_);                                                   \
    float D24 = updpf<DPP_ROR(8)>(C16, C16);                                  \
    float fv = (g==0) ? A_ : (g==1) ? B8 : (g==2) ? C16 : D24;                \
    float iv = (g==1) ? A_ : (g==0) ? B8 : (g==3) ? C16 : D24;                \
    float uv = (g==2) ? A_ : (g==3) ? B8 : (g==0) ? C16 : D24;                \
    float ov = (g==3) ? A_ : (g==2) ? B8 : (g==1) ? C16 : D24;                \
    c_own = fmaf(fv, c_own, iv * uv);                                         \
    float tc = fmaf(-2.0f, frcp(1.0f + fexp2(LOG2E2 * c_own)), 1.0f);         \
    h_own = ov * tc;                                                          \
    H[0] = h_own;                                                             \
    H[1] = updpf<DPP_QP(1,0,3,2)>(H[0], H[0]);                                \
    H[2] = updpf<DPP_QP(2,3,0,1)>(H[0], H[0]);                                \
    H[3] = updpf<DPP_QP(2,3,0,1)>(H[1], H[1]);                                \
    _Pragma("unroll")                                                         \
    for (int rr = 0; rr < 4; ++rr) {                                          \
        float yl = updpf<DPP_SHL(4)>(H[rr], H[rr]);                           \
        float yr = updpf<DPP_SHR(4)>(H[rr], H[rr]);                           \
        H[4 + rr] = m4 ? yr : yl;                                             \
    }                                                                         \
} while (0)

// MFMA one 16-step chunk from prefetched ua/va regs -> gbuf -> gv[16]
// A row = lane&15 = timestep-in-chunk (all rows distinct, M=16).
// C layout (proven r7/r8): col = lane&15, row = 4*(lane>>4)+reg.
#define MFMA_PHASE() do {                                                     \
    f32x4 acc0 = {0.f,0.f,0.f,0.f};                                           \
    f32x4 acc1 = {0.f,0.f,0.f,0.f};                                           \
    _Pragma("unroll")                                                         \
    for (int kc = 0; kc < 16; ++kc) {                                         \
        bf16x8 a = cvt8(ua[kc], va[kc]);                                      \
        const int kl_ = kc * 32 + q * 8;                                      \
        bf16x8 b0 = *reinterpret_cast<const bf16x8*>(&Wlds[lm][kl_]);         \
        bf16x8 b1 = *reinterpret_cast<const bf16x8*>(&Wlds[16 + lm][kl_]);    \
        acc0 = __builtin_amdgcn_mfma_f32_16x16x32_bf16(a, b0, acc0, 0, 0, 0); \
        acc1 = __builtin_amdgcn_mfma_f32_16x16x32_bf16(a, b1, acc1, 0, 0, 0); \
    }                                                                         \
    __syncthreads();                                                          \
    _Pragma("unroll")                                                         \
    for (int r_ = 0; r_ < 4; ++r_) {                                          \
        gbuf[(4*q + r_) * GBSTR + lm]      = fmaf(acc0[r_], INV2PI, bc0);     \
        gbuf[(4*q + r_) * GBSTR + 16 + lm] = fmaf(acc1[r_], INV2PI, bc1);     \
    }                                                                         \
    __syncthreads();                                                          \
    _Pragma("unroll")                                                         \
    for (int s_ = 0; s_ < 16; ++s_) gv[s_] = gbuf[s_ * GBSTR + l32];          \
} while (0)

// ---------------------------------------------------------------------------
// Fully fused kernel: 256 blocks x 1 wave; block = one batch row.
//   8 chunks of 16 timesteps. Per chunk: [issue tok(c+2)] [issue emb(c+1),
//   128 VGPR] [16 serial QSTEPs] [MFMA(c+1) -> gbuf -> gv]. The gather+GEMM
//   hide under the ~8.7k-cycle serial chain. One dispatch, no global G.
// ---------------------------------------------------------------------------
__global__ __launch_bounds__(64, 1)
void k_fused(const int* __restrict__ sent, const float* __restrict__ emb,
             const float* __restrict__ Wf, const float* __restrict__ Wi,
             const float* __restrict__ Wu, const float* __restrict__ Wo,
             const float* __restrict__ bf, const float* __restrict__ bi,
             const float* __restrict__ bu, const float* __restrict__ bo,
             const float* __restrict__ thf, const float* __restrict__ thi,
             const float* __restrict__ thu, const float* __restrict__ tho,
             float* __restrict__ out)
{
    __shared__ short Wlds[32][WROW];     // 33.5 KB bf16, [c][k 0..511]
    __shared__ float gbuf[16 * GBSTR];   // 2.56 KB chunk bounce

    const int tid = threadIdx.x;         // 0..63
    const int b   = blockIdx.x;          // batch row
    const int l32 = tid & 31;
    const int g   = l32 >> 3;            // gate 0..3 (f,i,u,o)
    const int j   = l32 & 7;             // qubit
    const int lm  = tid & 15;            // A-row (timestep-in-chunk) / B-col
    const int q   = tid >> 4;            // MFMA k-quarter

    // ---- stage W (EMBED cols) -> bf16 LDS (hw packed cvt) ----
    {
        const int c = tid & 31, seg = tid >> 5;      // seg 0..1 x 256 floats
        const int gg = c >> 3, jj = c & 7;
        const float* W = (gg==0) ? Wf : (gg==1) ? Wi : (gg==2) ? Wu : Wo;
        const float* src = W + (size_t)jj * DIN + seg * 256;
        #pragma unroll
        for (int p = 0; p < 32; ++p) {
            float4 u = *reinterpret_cast<const float4*>(src + p * 8);
            float4 v = *reinterpret_cast<const float4*>(src + p * 8 + 4);
            *reinterpret_cast<bf16x8*>(&Wlds[c][seg * 256 + p * 8]) = cvt8(u, v);
        }
    }

    // epilogue fold constants for this lane's two C columns (lm, 16+lm)
    float bc0, bc1;
    {
        const int g0 = lm >> 3, j0 = lm & 7;         // col lm   -> gate 0/1
        const float* B0 = (g0==0) ? bf  : bi;
        const float* T0 = (g0==0) ? thf : thi;
        bc0 = (B0[j0] + T0[j0]) * INV2PI;
        const float* B1 = (g0==0) ? bu  : bo;        // col 16+lm -> gate 2/3
        const float* T1 = (g0==0) ? thu : tho;
        bc1 = (B1[j0] + T1[j0]) * INV2PI;
    }

    // QSTEP weights: permuted, pre-scaled; dot = sum_r H[r]*Whp[r], H[r]=h[j^r]
    const float* Wsel = (g==0) ? Wf : (g==1) ? Wi : (g==2) ? Wu : Wo;
    float Whp[8];
    #pragma unroll
    for (int rr = 0; rr < 8; ++rr)
        Whp[rr] = Wsel[j * DIN + EMBED + (j ^ rr)] * INV2PI;

    __syncthreads();

    // ---- prologue: chunk 0 loads + MFMA ----
    float4 ua[16], va[16];
    float  gv[16];
    {
        int tok0 = sent[lm * BATCHN + b];
        const float* ar = emb + (size_t)tok0 * EMBED;
        #pragma unroll
        for (int kc = 0; kc < 16; ++kc) {
            ua[kc] = *reinterpret_cast<const float4*>(ar + kc * 32 + q * 8);
            va[kc] = *reinterpret_cast<const float4*>(ar + kc * 32 + q * 8 + 4);
        }
    }
    int tokN = sent[(16 + lm) * BATCHN + b];
    MFMA_PHASE();

    // ---- serial state ----
    float H[8];
    #pragma unroll
    for (int rr = 0; rr < 8; ++rr) H[rr] = 0.f;
    float c_own = 0.f, h_own = 0.f;

    const bool m1 = (j >= 1), m2 = (j >= 2), m4 = (j >= 4), jz = (j == 0);
    const bool isU = (g == 2);
    const float ek = isU ? LOG2E2 : -LOG2E;
    const float sk = isU ? -2.0f  : 1.0f;
    const float ok = isU ? 1.0f   : 0.0f;

    #pragma unroll 1
    for (int c = 0; c < 8; ++c) {
        int tokNN = 0;
        if (c < 6) tokNN = sent[((c + 2) * 16 + lm) * BATCHN + b];
        if (c < 7) {
            const float* an = emb + (size_t)tokN * EMBED;
            #pragma unroll
            for (int kc = 0; kc < 16; ++kc) {
                ua[kc] = *reinterpret_cast<const float4*>(an + kc * 32 + q * 8);
                va[kc] = *reinterpret_cast<const float4*>(an + kc * 32 + q * 8 + 4);
            }
        }
        asm volatile("" ::: "memory");   // pin prefetch issue before QSTEPs

        #pragma unroll
        for (int s = 0; s < 16; ++s) QSTEP(gv[s]);

        if (c < 7) MFMA_PHASE();
        tokN = tokNN;
    }

    if (tid < 8) out[b * NQ + tid] = h_own;   // lanes 0-7: g=0, j=tid
}

// ---------------------------------------------------------------------------
extern "C" void kernel_launch(void* const* d_in, const int* in_sizes, int n_in,
                              void* d_out, int out_size, void* d_ws, size_t ws_size,
                              hipStream_t stream)
{
    const int*   sent = (const int*)  d_in[0];
    // d_in[1] = features : unused by the reference
    const float* emb  = (const float*)d_in[2];
    const float* Wf   = (const float*)d_in[3];
    const float* bf   = (const float*)d_in[4];
    const float* Wi   = (const float*)d_in[5];
    const float* bi   = (const float*)d_in[6];
    const float* Wu   = (const float*)d_in[7];
    const float* bu   = (const float*)d_in[8];
    const float* Wo   = (const float*)d_in[9];
    const float* bo   = (const float*)d_in[10];
    const float* thf  = (const float*)d_in[11];
    const float* thi  = (const float*)d_in[12];
    const float* thu  = (const float*)d_in[13];
    const float* tho  = (const float*)d_in[14];
    float* out = (float*)d_out;

    k_fused<<<BATCHN, 64, 0, stream>>>(sent, emb, Wf, Wi, Wu, Wo,
                                       bf, bi, bu, bo,
                                       thf, thi, thu, tho, out);
}

// Round 17
// 35.793 us; speedup vs baseline: 1.5269x; 1.2283x over previous
//
#include <hip/hip_runtime.h>
#include <hip/hip_bf16.h>

#define NQ     8
#define SEQL   128
#define BATCHN 256
#define EMBED  512
#define DIN    520          // EMBED + NQ
#define GSTR   32           // 4 gates * 8 qubits
#define GBSTR  40           // gbuf row stride (floats)
#define INV2PI 0.15915494309189535f
#define WROW   524          // Wlds padded row (shorts) -> conflict-free b128

typedef __attribute__((ext_vector_type(8))) short  bf16x8;
typedef __attribute__((ext_vector_type(4))) float  f32x4;
typedef unsigned int uint2v __attribute__((ext_vector_type(2)));

// 8 f32 -> bf16x8 via hardware v_cvt_pk_bf16_f32 (RNE)
__device__ __forceinline__ bf16x8 cvt8(float4 u, float4 v) {
    union { unsigned w[4]; bf16x8 v8; } r;
    asm("v_cvt_pk_bf16_f32 %0, %1, %2" : "=v"(r.w[0]) : "v"(u.x), "v"(u.y));
    asm("v_cvt_pk_bf16_f32 %0, %1, %2" : "=v"(r.w[1]) : "v"(u.z), "v"(u.w));
    asm("v_cvt_pk_bf16_f32 %0, %1, %2" : "=v"(r.w[2]) : "v"(v.x), "v"(v.y));
    asm("v_cvt_pk_bf16_f32 %0, %1, %2" : "=v"(r.w[3]) : "v"(v.z), "v"(v.w));
    return r.v8;
}

// ---------------------------------------------------------------------------
// DPP helpers
// ---------------------------------------------------------------------------
#define DPP_QP(a,b,c,d) ((a)|((b)<<2)|((c)<<4)|((d)<<6))
#define DPP_SHL(n) (0x100+(n))
#define DPP_SHR(n) (0x110+(n))
#define DPP_ROR(n) (0x120+(n))

template<int CTRL>
__device__ __forceinline__ float updpf(float old_, float src) {
    return __int_as_float(__builtin_amdgcn_update_dpp(
        __float_as_int(old_), __float_as_int(src), CTRL, 0xF, 0xF, false));
}

// value at lane^16 (XOR-extract, semantics-proof)
__device__ __forceinline__ float xor16f(float x) {
    unsigned xu = (unsigned)__float_as_int(x);
    uint2v r = __builtin_amdgcn_permlane16_swap(xu, xu, false, false);
    return __int_as_float((int)(r.x ^ r.y ^ xu));
}

__device__ __forceinline__ float frcp(float x) { return __builtin_amdgcn_rcpf(x); }
__device__ __forceinline__ float fexp2(float x) { return __builtin_amdgcn_exp2f(x); }

#define LOG2E  1.4426950408889634f
#define LOG2E2 2.8853900817779268f

// one LSTM step (r8-proven math)
#define QSTEP(GV) do {                                                        \
    float sA = fmaf(H[0],Whp[0],fmaf(H[1],Whp[1],fmaf(H[2],Whp[2],H[3]*Whp[3]))); \
    float sB = fmaf(H[4],Whp[4],fmaf(H[5],Whp[5],fmaf(H[6],Whp[6],H[7]*Whp[7]))); \
    float cs = __builtin_amdgcn_cosf((GV) + sA + sB);                         \
    float p = cs, s;                                                          \
    s = updpf<DPP_SHR(1)>(1.0f, p); p *= (m1 ? s : 1.0f);                     \
    s = updpf<DPP_SHR(2)>(1.0f, p); p *= (m2 ? s : 1.0f);                     \
    s = updpf<DPP_SHR(4)>(1.0f, p); p *= (m4 ? s : 1.0f);                     \
    float v = jz ? 1.0f : cs;                                                 \
    v *= updpf<DPP_QP(1,0,3,2)>(v, v);                                        \
    v *= updpf<DPP_QP(2,3,0,1)>(v, v);                                        \
    float xl = updpf<DPP_SHL(4)>(v, v);                                       \
    float xr = updpf<DPP_SHR(4)>(v, v);                                       \
    v *= (m4 ? xr : xl);                                                      \
    float qv = jz ? v : p;                                                    \
    float act = fmaf(sk, frcp(1.0f + fexp2(ek * qv)), ok);                    \
    float A_  = act;                                                          \
    float B8  = updpf<DPP_ROR(8)>(A_, A_);                                    \
    float C16 = xor16f(A_);                                                   \
    float D24 = updpf<DPP_ROR(8)>(C16, C16);                                  \
    float fv = (g==0) ? A_ : (g==1) ? B8 : (g==2) ? C16 : D24;                \
    float iv = (g==1) ? A_ : (g==0) ? B8 : (g==3) ? C16 : D24;                \
    float uv = (g==2) ? A_ : (g==3) ? B8 : (g==0) ? C16 : D24;                \
    float ov = (g==3) ? A_ : (g==2) ? B8 : (g==1) ? C16 : D24;                \
    c_own = fmaf(fv, c_own, iv * uv);                                         \
    float tc = fmaf(-2.0f, frcp(1.0f + fexp2(LOG2E2 * c_own)), 1.0f);         \
    h_own = ov * tc;                                                          \
    H[0] = h_own;                                                             \
    H[1] = updpf<DPP_QP(1,0,3,2)>(H[0], H[0]);                                \
    H[2] = updpf<DPP_QP(2,3,0,1)>(H[0], H[0]);                                \
    H[3] = updpf<DPP_QP(2,3,0,1)>(H[1], H[1]);                                \
    _Pragma("unroll")                                                         \
    for (int rr = 0; rr < 4; ++rr) {                                          \
        float yl = updpf<DPP_SHL(4)>(H[rr], H[rr]);                           \
        float yr = updpf<DPP_SHR(4)>(H[rr], H[rr]);                           \
        H[4 + rr] = m4 ? yr : yl;                                             \
    }                                                                         \
} while (0)

// producer: gather chunk CH's 16 emb rows, MFMA vs Wlds, write G vals to DST.
// A row = lm = timestep-in-chunk; C layout col=lm(+16), row=4q+reg (proven).
#define PRODUCE(DST, CH) do {                                                 \
    int tok_ = sent[((CH) * 16 + lm) * BATCHN + b];                           \
    const float* ar_ = emb + (size_t)tok_ * EMBED;                            \
    float4 ua[16], va[16];                                                    \
    _Pragma("unroll")                                                         \
    for (int kc = 0; kc < 16; ++kc) {                                         \
        ua[kc] = *reinterpret_cast<const float4*>(ar_ + kc * 32 + q * 8);     \
        va[kc] = *reinterpret_cast<const float4*>(ar_ + kc * 32 + q * 8 + 4); \
    }                                                                         \
    f32x4 acc0 = {0.f,0.f,0.f,0.f};                                           \
    f32x4 acc1 = {0.f,0.f,0.f,0.f};                                           \
    _Pragma("unroll")                                                         \
    for (int kc = 0; kc < 16; ++kc) {                                         \
        bf16x8 a_ = cvt8(ua[kc], va[kc]);                                     \
        const int kl_ = kc * 32 + q * 8;                                      \
        bf16x8 b0_ = *reinterpret_cast<const bf16x8*>(&Wlds[lm][kl_]);        \
        bf16x8 b1_ = *reinterpret_cast<const bf16x8*>(&Wlds[16 + lm][kl_]);   \
        acc0 = __builtin_amdgcn_mfma_f32_16x16x32_bf16(a_, b0_, acc0, 0,0,0); \
        acc1 = __builtin_amdgcn_mfma_f32_16x16x32_bf16(a_, b1_, acc1, 0,0,0); \
    }                                                                         \
    _Pragma("unroll")                                                         \
    for (int r_ = 0; r_ < 4; ++r_) {                                          \
        (DST)[(4*q + r_) * GBSTR + lm]      = fmaf(acc0[r_], INV2PI, bc0);    \
        (DST)[(4*q + r_) * GBSTR + 16 + lm] = fmaf(acc1[r_], INV2PI, bc1);    \
    }                                                                         \
} while (0)

// ---------------------------------------------------------------------------
// Wave-specialized fused kernel: 256 blocks x 128 threads (2 waves).
//   wave 0 (consumer): ONLY the serial LSTM chain, reading G from gbuf.
//   wave 1 (producer): tok gather + emb gather + MFMA for chunk c+1 into
//   gbuf[(c+1)&1] while consumer processes chunk c. One barrier per chunk.
//   All producer overhead (loads/cvt/MFMA/ds) leaves the serial wave.
// ---------------------------------------------------------------------------
__global__ __launch_bounds__(128, 1)
void k_fused(const int* __restrict__ sent, const float* __restrict__ emb,
             const float* __restrict__ Wf, const float* __restrict__ Wi,
             const float* __restrict__ Wu, const float* __restrict__ Wo,
             const float* __restrict__ bf, const float* __restrict__ bi,
             const float* __restrict__ bu, const float* __restrict__ bo,
             const float* __restrict__ thf, const float* __restrict__ thi,
             const float* __restrict__ thu, const float* __restrict__ tho,
             float* __restrict__ out)
{
    __shared__ short Wlds[32][WROW];        // 33.5 KB bf16, [c][k 0..511]
    __shared__ float gbuf[2][16 * GBSTR];   // 5.1 KB double-buffered chunk

    const int tid = threadIdx.x;            // 0..127
    const int b   = blockIdx.x;             // batch row
    const bool producer = (tid >= 64);
    const int l32 = tid & 31;               // consumer lane
    const int g   = l32 >> 3;
    const int j   = l32 & 7;
    const int lm  = tid & 15;               // producer A-row / B-col
    const int q   = (tid >> 4) & 3;         // producer k-quarter

    // ---- stage W -> bf16 LDS, 128 threads cooperatively ----
    {
        const int c = tid & 31, seg = tid >> 5;     // seg 0..3 x 128 floats
        const int gg = c >> 3, jj = c & 7;
        const float* W = (gg==0) ? Wf : (gg==1) ? Wi : (gg==2) ? Wu : Wo;
        const float* src = W + (size_t)jj * DIN + seg * 128;
        #pragma unroll
        for (int p = 0; p < 16; ++p) {
            float4 u = *reinterpret_cast<const float4*>(src + p * 8);
            float4 v = *reinterpret_cast<const float4*>(src + p * 8 + 4);
            *reinterpret_cast<bf16x8*>(&Wlds[c][seg * 128 + p * 8]) = cvt8(u, v);
        }
    }

    // ---- role-specific persistent state (declared at scope for QSTEP) ----
    float Whp[8], H[8];
    float c_own = 0.f, h_own = 0.f;
    float bc0 = 0.f, bc1 = 0.f;
    bool  m1 = false, m2 = false, m4 = false, jz = false;
    float ek = 0.f, sk = 0.f, ok = 0.f;

    if (producer) {
        const int g0 = lm >> 3, j0 = lm & 7;        // col lm -> gate 0/1
        const float* B0 = (g0==0) ? bf  : bi;
        const float* T0 = (g0==0) ? thf : thi;
        bc0 = (B0[j0] + T0[j0]) * INV2PI;
        const float* B1 = (g0==0) ? bu  : bo;       // col 16+lm -> gate 2/3
        const float* T1 = (g0==0) ? thu : tho;
        bc1 = (B1[j0] + T1[j0]) * INV2PI;
    } else {
        const float* Wsel = (g==0) ? Wf : (g==1) ? Wi : (g==2) ? Wu : Wo;
        #pragma unroll
        for (int rr = 0; rr < 8; ++rr) {
            Whp[rr] = Wsel[j * DIN + EMBED + (j ^ rr)] * INV2PI;
            H[rr]   = 0.f;
        }
        m1 = (j >= 1); m2 = (j >= 2); m4 = (j >= 4); jz = (j == 0);
        const bool isU = (g == 2);
        ek = isU ? LOG2E2 : -LOG2E;
        sk = isU ? -2.0f  : 1.0f;
        ok = isU ? 1.0f   : 0.0f;
    }
    __syncthreads();                         // Wlds ready

    if (producer) PRODUCE(&gbuf[0][0], 0);   // prologue: chunk 0
    __syncthreads();                         // gbuf[0] ready

    #pragma unroll 1
    for (int c = 0; c < 8; ++c) {
        if (producer) {
            if (c < 7) PRODUCE(&gbuf[(c + 1) & 1][0], c + 1);
        } else {
            const float* gc = &gbuf[c & 1][l32];
            float n0 = gc[0];
            #pragma unroll
            for (int s = 0; s < 16; ++s) {
                float nn = (s < 15) ? gc[(s + 1) * GBSTR] : 0.f;
                QSTEP(n0);
                n0 = nn;
            }
        }
        __syncthreads();
    }

    if (tid < 8) out[b * NQ + tid] = h_own;  // consumer lanes 0-7: g=0, j=tid
}

// ---------------------------------------------------------------------------
extern "C" void kernel_launch(void* const* d_in, const int* in_sizes, int n_in,
                              void* d_out, int out_size, void* d_ws, size_t ws_size,
                              hipStream_t stream)
{
    const int*   sent = (const int*)  d_in[0];
    // d_in[1] = features : unused by the reference
    const float* emb  = (const float*)d_in[2];
    const float* Wf   = (const float*)d_in[3];
    const float* bf   = (const float*)d_in[4];
    const float* Wi   = (const float*)d_in[5];
    const float* bi   = (const float*)d_in[6];
    const float* Wu   = (const float*)d_in[7];
    const float* bu   = (const float*)d_in[8];
    const float* Wo   = (const float*)d_in[9];
    const float* bo   = (const float*)d_in[10];
    const float* thf  = (const float*)d_in[11];
    const float* thi  = (const float*)d_in[12];
    const float* thu  = (const float*)d_in[13];
    const float* tho  = (const float*)d_in[14];
    float* out = (float*)d_out;

    k_fused<<<BATCHN, 128, 0, stream>>>(sent, emb, Wf, Wi, Wu, Wo,
                                        bf, bi, bu, bo,
                                        thf, thi, thu, tho, out);
}